// Round 3
// baseline (158.026 us; speedup 1.0000x reference)
//
#include <hip/hip_runtime.h>
#include <hip/hip_bf16.h>
#include <math.h>

// spatialAttention: B=512, P=128, D=64, domain 12x12, W [64,128], out [512,128,64] f32
#define NB 512
#define NP 128
#define ND 64
#define EPSF 1e-5f
// bf16-element row stride for MFMA-read LDS arrays: 136 elems = 272 B.
// 272 % 16 == 0 -> every short8 frag access is 16B-aligned; frag-read bank
// aliasing is 2-way (free per m136).
#define SW 136

typedef __attribute__((ext_vector_type(8))) short short8;   // 8 bf16 = 4 VGPRs
typedef __attribute__((ext_vector_type(4))) float f32x4;    // MFMA accumulator

__device__ __forceinline__ short f2bf(float x) {
    __hip_bfloat16 h = __float2bfloat16(x);
    return *reinterpret_cast<short*>(&h);
}

// bin = floor(x/30) clamped to [0,11]. f64 multiply by RN64(1/30) then RN to
// f32 agrees with numpy's RN32(x/30) except w.p. ~2^-29/elem. x >= 0 here.
__device__ __forceinline__ int bin30(float x) {
    float t = (float)((double)x * (1.0 / 30.0));
    int i = (int)t;
    return i < 0 ? 0 : (i > 11 ? 11 : i);
}

__device__ __forceinline__ float fast_tanh(float x) {
    float e = __expf(2.0f * x);                    // ~1 ulp native exp
    return 1.0f - 2.0f * __builtin_amdgcn_rcpf(e + 1.0f);
}

// W as bf16 [64][128], produced by prep kernel each launch (graph-safe).
__device__ __align__(16) short g_wbf[ND * 2 * ND];

__global__ __launch_bounds__(256) void prep_w(const float* __restrict__ W) {
    int idx = blockIdx.x * 256 + threadIdx.x;     // 2048 float4
    float4 v = ((const float4*)W)[idx];
    short4 s4;
    s4.x = f2bf(v.x); s4.y = f2bf(v.y); s4.z = f2bf(v.z); s4.w = f2bf(v.w);
    *(short4*)&g_wbf[idx * 4] = s4;
}

// Compute 8 E values (cols c0..c0+7 of row p) in bf16, packed for the MFMA
// A-fragment. All inputs already in registers.
__device__ __forceinline__ short8 calc_e8(
    float4 d0, float4 d1, float4 b0, float4 b1, float4 h0, float4 h1,
    float4 m0, float4 m1, const float* s_dom, float mp, int c0, int p)
{
    float dv[8] = {d0.x, d0.y, d0.z, d0.w, d1.x, d1.y, d1.z, d1.w};
    float bv[8] = {b0.x, b0.y, b0.z, b0.w, b1.x, b1.y, b1.z, b1.w};
    float hv[8] = {h0.x, h0.y, h0.z, h0.w, h1.x, h1.y, h1.z, h1.w};
    float mv[8] = {m0.x, m0.y, m0.z, m0.w, m1.x, m1.y, m1.z, m1.w};
    short8 a;
    #pragma unroll
    for (int j = 0; j < 8; ++j) {
        int i1 = bin30(hv[j]), i2 = bin30(bv[j]);
        float wv = s_dom[i1 * 12 + i2] - dv[j];
        bool on = (wv > 0.0f) && (mp != 0.0f) && (mv[j] != 0.0f) && (c0 + j != p);
        a[j] = f2bf(on ? (__expf(wv) + EPSF) : EPSF);
    }
    return a;
}

// R7 restructure (resubmit after container-level infra failure; only change
// vs R2 submission: __align__(16) on s_dom/s_mask so float4 LDS reads are
// guaranteed-aligned ds_read_b128): E never touches LDS. R0/R1 post-mortem:
// occupancy 34->66% with identical 48 us duration, all pipes <25% busy ->
// the cost is the barrier-serialized {load}->{LDS round-trip}->{MFMA}
// structure, not wave count. Each wave computes its 16-row tile's E directly
// in MFMA A-fragment layout (lane l16 = row, quad*8+kb*32+j = col): no E
// ds_write, no E frag read, no h-passthrough copy, ONE block barrier total.
// Phase-1 global loads (24 independent float4/lane) overlap MFMA issue.
//   stage:   h -> s_hT (bf16, transposed, swizzled) AND h-cols of fused s_w
//            (row-major, natural layout); dom/mask -> LDS. One barrier.
//   phase 1: E A-frags in registers (kb=0,1 loads pre-issued before barrier).
//   phase 2: wh_unnorm = E @ h + ones-MFMA row sums; scale by 1/(s+eps);
//            wave-local wh write into fused s_w (DS in-order per wave).
//   phase 3: out = fast_tanh(fused @ W^T + b), W-frags from g_wbf (L2-hot).
__global__ __launch_bounds__(256, 4) void spatial_attn_kernel(
    const float* __restrict__ hidden,   // [B,P,D]
    const float* __restrict__ dist,     // [B,P,P]
    const float* __restrict__ bear,     // [B,P,P]
    const float* __restrict__ head,     // [B,P,P]
    const float* __restrict__ smask,    // [B,P]
    const float* __restrict__ domain,   // [12,12]
    const float* __restrict__ bias,     // [D]
    float* __restrict__ out)            // [B,P,D]
{
    __shared__ __align__(16) short s_w[64 * SW];   // 17408 B: fused [wh|h]
    __shared__ __align__(16) short s_hT[ND * SW];  // 17408 B: s_hT[d][q]=h[q][d]
    __shared__ __align__(16) float s_dom[144];
    __shared__ __align__(16) float s_mask[NP];

    const int blk  = blockIdx.x;
    const int b    = blk >> 1;
    const int half = blk & 1;
    const int tid  = threadIdx.x;
    const int lane = tid & 63;
    const int wave = tid >> 6;          // 0..3
    const int quad = lane >> 4;
    const int l16  = lane & 15;

    const int R0L = wave * 16;          // local row base (of 64)
    const int row = R0L + l16;          // this lane's E row (local)
    const int p   = half * 64 + row;    // this lane's E row (within batch)
    const size_t rowbase = (size_t)b * NP * NP;
    const float* dr = dist + rowbase + (size_t)p * NP;
    const float* br = bear + rowbase + (size_t)p * NP;
    const float* hr = head + rowbase + (size_t)p * NP;

    // ---- pre-issue phase-1 loads for kb=0,1 (independent of LDS) ----
    const int c0a = quad * 8;            // kb=0 column base
    const int c0b = 32 + quad * 8;       // kb=1 column base
    float4 pd0 = *(const float4*)(dr + c0a), pd1 = *(const float4*)(dr + c0a + 4);
    float4 pb0 = *(const float4*)(br + c0a), pb1 = *(const float4*)(br + c0a + 4);
    float4 ph0 = *(const float4*)(hr + c0a), ph1 = *(const float4*)(hr + c0a + 4);
    float4 qd0 = *(const float4*)(dr + c0b), qd1 = *(const float4*)(dr + c0b + 4);
    float4 qb0 = *(const float4*)(br + c0b), qb1 = *(const float4*)(br + c0b + 4);
    float4 qh0 = *(const float4*)(hr + c0b), qh1 = *(const float4*)(hr + c0b + 4);

    // ---- stage h: s_hT (transposed, swizzled perm) + h-cols of fused s_w ----
    {
        const float4* hsrc = (const float4*)(hidden + (size_t)b * NP * ND);
        #pragma unroll
        for (int i = 0; i < 8; ++i) {
            int idx = i * 256 + ((tid & 15) * 16 + (tid >> 4));  // bijective
            float4 v = hsrc[idx];
            int q = idx >> 4;            // 0..127
            int d = (idx & 15) * 4;      // 0..60
            short4 s4;
            s4.x = f2bf(v.x); s4.y = f2bf(v.y); s4.z = f2bf(v.z); s4.w = f2bf(v.w);
            s_hT[(d + 0) * SW + q] = s4.x;
            s_hT[(d + 1) * SW + q] = s4.y;
            s_hT[(d + 2) * SW + q] = s4.z;
            s_hT[(d + 3) * SW + q] = s4.w;
            int qloc = q - half * 64;
            if (qloc >= 0 && qloc < 64)   // h-cols of fused rows, natural layout
                *(short4*)&s_w[qloc * SW + 64 + d] = s4;
        }
    }
    if (tid < 144) s_dom[tid] = domain[tid];
    if (tid < NP)  s_mask[tid] = smask[b * NP + tid];
    __syncthreads();   // the ONLY block-wide barrier

    // ---- phase 1: E A-frags in registers ----
    const float mp = s_mask[p];
    short8 afr[4];
    {
        float4 m0 = *(const float4*)&s_mask[c0a];
        float4 m1 = *(const float4*)&s_mask[c0a + 4];
        afr[0] = calc_e8(pd0, pd1, pb0, pb1, ph0, ph1, m0, m1, s_dom, mp, c0a, p);
        float4 n0 = *(const float4*)&s_mask[c0b];
        float4 n1 = *(const float4*)&s_mask[c0b + 4];
        afr[1] = calc_e8(qd0, qd1, qb0, qb1, qh0, qh1, n0, n1, s_dom, mp, c0b, p);
    }
    #pragma unroll
    for (int kb = 2; kb < 4; ++kb) {
        const int c0 = kb * 32 + quad * 8;
        float4 d0 = *(const float4*)(dr + c0), d1 = *(const float4*)(dr + c0 + 4);
        float4 b0 = *(const float4*)(br + c0), b1 = *(const float4*)(br + c0 + 4);
        float4 h0 = *(const float4*)(hr + c0), h1 = *(const float4*)(hr + c0 + 4);
        float4 m0 = *(const float4*)&s_mask[c0];
        float4 m1 = *(const float4*)&s_mask[c0 + 4];
        afr[kb] = calc_e8(d0, d1, b0, b1, h0, h1, m0, m1, s_dom, mp, c0, p);
    }

    // ---- phase 2: wh_unnorm = E @ h + ones-MFMA row sums (K=128) ----
    f32x4 acc[4], accs;
    #pragma unroll
    for (int tj = 0; tj < 4; ++tj) acc[tj] = (f32x4){0.f, 0.f, 0.f, 0.f};
    accs = (f32x4){0.f, 0.f, 0.f, 0.f};

    short8 ones;
    #pragma unroll
    for (int i = 0; i < 8; ++i) ones[i] = (short)0x3F80;  // bf16 1.0

    #pragma unroll
    for (int kb = 0; kb < 4; ++kb) {
        const int ko = kb * 32 + quad * 8;
        accs = __builtin_amdgcn_mfma_f32_16x16x32_bf16(afr[kb], ones, accs, 0, 0, 0);
        #pragma unroll
        for (int tj = 0; tj < 4; ++tj) {
            short8 bf = *(const short8*)&s_hT[(tj * 16 + l16) * SW + ko];
            acc[tj] = __builtin_amdgcn_mfma_f32_16x16x32_bf16(afr[kb], bf, acc[tj], 0, 0, 0);
        }
    }

    // C/D row = quad*4 + r; accs rows match lane-for-lane.
    float inv[4];
    #pragma unroll
    for (int r = 0; r < 4; ++r) inv[r] = 1.0f / (accs[r] + EPSF);

    // ---- wh into fused s_w (wave-local rows; DS is in-order per wave) ----
    #pragma unroll
    for (int tj = 0; tj < 4; ++tj)
        #pragma unroll
        for (int r = 0; r < 4; ++r) {
            int rw = R0L + quad * 4 + r;
            s_w[rw * SW + tj * 16 + l16] = f2bf(acc[tj][r] * inv[r]);
        }

    // ---- phase 3: out = tanh(fused @ W^T + b), B-frags from g_wbf (L2) ----
    f32x4 acc2[4];
    #pragma unroll
    for (int tj = 0; tj < 4; ++tj) acc2[tj] = (f32x4){0.f, 0.f, 0.f, 0.f};

    #pragma unroll
    for (int kb = 0; kb < 4; ++kb) {
        const int ko = kb * 32 + quad * 8;
        short8 a = *(const short8*)&s_w[(R0L + l16) * SW + ko];
        #pragma unroll
        for (int tj = 0; tj < 4; ++tj) {
            short8 bf = *(const short8*)&g_wbf[(tj * 16 + l16) * (2 * ND) + ko];
            acc2[tj] = __builtin_amdgcn_mfma_f32_16x16x32_bf16(a, bf, acc2[tj], 0, 0, 0);
        }
    }

    float bvals[4];
    #pragma unroll
    for (int tj = 0; tj < 4; ++tj) bvals[tj] = bias[tj * 16 + l16];

    float* ob = out + ((size_t)b * NP + half * 64) * ND;
    #pragma unroll
    for (int tj = 0; tj < 4; ++tj)
        #pragma unroll
        for (int r = 0; r < 4; ++r) {
            int rw = R0L + quad * 4 + r;
            ob[(size_t)rw * ND + tj * 16 + l16] = fast_tanh(acc2[tj][r] + bvals[tj]);
        }
}

extern "C" void kernel_launch(void* const* d_in, const int* in_sizes, int n_in,
                              void* d_out, int out_size, void* d_ws, size_t ws_size,
                              hipStream_t stream) {
    const float* hidden = (const float*)d_in[0];
    const float* dist   = (const float*)d_in[1];
    const float* bear   = (const float*)d_in[2];
    const float* head   = (const float*)d_in[3];
    const float* smask  = (const float*)d_in[4];
    const float* domain = (const float*)d_in[5];
    const float* W      = (const float*)d_in[6];
    const float* bias   = (const float*)d_in[7];
    float* out = (float*)d_out;

    prep_w<<<dim3(8), dim3(256), 0, stream>>>(W);
    spatial_attn_kernel<<<dim3(NB * 2), dim3(256), 0, stream>>>(
        hidden, dist, bear, head, smask, domain, bias, out);
}

// Round 4
// 153.364 us; speedup vs baseline: 1.0304x; 1.0304x over previous
//
#include <hip/hip_runtime.h>
#include <hip/hip_bf16.h>
#include <math.h>

// spatialAttention: B=512, P=128, D=64, domain 12x12, W [64,128], out [512,128,64] f32
#define NB 512
#define NP 128
#define ND 64
#define EPSF 1e-5f
// bf16-element row stride for MFMA-read LDS arrays: 136 elems = 272 B.
// 272 % 16 == 0 -> every short8 frag access is 16B-aligned; frag-read bank
// aliasing is 2-way (free per m136).
#define SW 136

typedef __attribute__((ext_vector_type(8))) short short8;   // 8 bf16 = 4 VGPRs
typedef __attribute__((ext_vector_type(4))) float f32x4;    // MFMA accumulator

__device__ __forceinline__ short f2bf(float x) {
    __hip_bfloat16 h = __float2bfloat16(x);
    return *reinterpret_cast<short*>(&h);
}

// bin = floor(x/30) clamped to [0,11]. f64 multiply by RN64(1/30) then RN to
// f32 agrees with numpy's RN32(x/30) except w.p. ~2^-29/elem. x >= 0 here.
__device__ __forceinline__ int bin30(float x) {
    float t = (float)((double)x * (1.0 / 30.0));
    int i = (int)t;
    return i < 0 ? 0 : (i > 11 ? 11 : i);
}

__device__ __forceinline__ float fast_tanh(float x) {
    float e = __expf(2.0f * x);                    // ~1 ulp native exp
    return 1.0f - 2.0f * __builtin_amdgcn_rcpf(e + 1.0f);
}

// W as bf16 [64][128], produced by prep kernel each launch (graph-safe).
__device__ __align__(16) short g_wbf[ND * 2 * ND];

__global__ __launch_bounds__(256) void prep_w(const float* __restrict__ W) {
    int idx = blockIdx.x * 256 + threadIdx.x;     // 2048 float4
    float4 v = ((const float4*)W)[idx];
    short4 s4;
    s4.x = f2bf(v.x); s4.y = f2bf(v.y); s4.z = f2bf(v.z); s4.w = f2bf(v.w);
    *(short4*)&g_wbf[idx * 4] = s4;
}

// Compute 8 E values (cols c0..c0+7 of row p) in bf16, packed for the MFMA
// A-fragment. All inputs already in registers.
__device__ __forceinline__ short8 calc_e8(
    float4 d0, float4 d1, float4 b0, float4 b1, float4 h0, float4 h1,
    float4 m0, float4 m1, const float* s_dom, float mp, int c0, int p)
{
    float dv[8] = {d0.x, d0.y, d0.z, d0.w, d1.x, d1.y, d1.z, d1.w};
    float bv[8] = {b0.x, b0.y, b0.z, b0.w, b1.x, b1.y, b1.z, b1.w};
    float hv[8] = {h0.x, h0.y, h0.z, h0.w, h1.x, h1.y, h1.z, h1.w};
    float mv[8] = {m0.x, m0.y, m0.z, m0.w, m1.x, m1.y, m1.z, m1.w};
    short8 a;
    #pragma unroll
    for (int j = 0; j < 8; ++j) {
        int i1 = bin30(hv[j]), i2 = bin30(bv[j]);
        float wv = s_dom[i1 * 12 + i2] - dv[j];
        bool on = (wv > 0.0f) && (mp != 0.0f) && (mv[j] != 0.0f) && (c0 + j != p);
        a[j] = f2bf(on ? (__expf(wv) + EPSF) : EPSF);
    }
    return a;
}

// R8: forced memory-level parallelism. R0/R1/R3 post-mortem: three different
// structures all 45-50us, all pipes idle, VGPR 52 in R3 proved the compiler
// sank the "pre-issued" loads and serialized phase 1 into ~5-load batches
// (demand 134MB/48us = 4.6B/cy/CU -> only ~2.7KB in flight per CU vs ~9.2KB
// needed for BW saturation). Fix: batch-issue loads and fence with
// sched_barrier(0) so the compiler cannot sink/serialize them:
//   pre-barrier:  issue 8 hidden f4 + 12 kb{0,1} f4 back-to-back, fence;
//                 stage h (counted waits consume hidden while kb01 in
//                 flight); barrier drain pays ONE latency for the batch.
//   post-barrier: issue 12 kb{2,3} f4, fence; compute E+MFMA for kb{0,1}
//                 (kb23 latency hides under ~800cy of exp/VALU + MFMA);
//                 compute E+MFMA kb{2,3}; phases 2-end/3 as R3.
// launch_bounds(256,3): 170-VGPR budget so the allocator can't re-serialize
// (spill at 128 would be worse; LDS caps blocks/CU at 4 regardless).
// MFMA accumulation order unchanged (kb ascending) -> bitwise-identical out.
__global__ __launch_bounds__(256, 3) void spatial_attn_kernel(
    const float* __restrict__ hidden,   // [B,P,D]
    const float* __restrict__ dist,     // [B,P,P]
    const float* __restrict__ bear,     // [B,P,P]
    const float* __restrict__ head,     // [B,P,P]
    const float* __restrict__ smask,    // [B,P]
    const float* __restrict__ domain,   // [12,12]
    const float* __restrict__ bias,     // [D]
    float* __restrict__ out)            // [B,P,D]
{
    __shared__ __align__(16) short s_w[64 * SW];   // 17408 B: fused [wh|h]
    __shared__ __align__(16) short s_hT[ND * SW];  // 17408 B: s_hT[d][q]=h[q][d]
    __shared__ __align__(16) float s_dom[144];
    __shared__ __align__(16) float s_mask[NP];

    const int blk  = blockIdx.x;
    const int b    = blk >> 1;
    const int half = blk & 1;
    const int tid  = threadIdx.x;
    const int lane = tid & 63;
    const int wave = tid >> 6;          // 0..3
    const int quad = lane >> 4;
    const int l16  = lane & 15;

    const int R0L = wave * 16;          // local row base (of 64)
    const int row = R0L + l16;          // this lane's E row (local)
    const int p   = half * 64 + row;    // this lane's E row (within batch)
    const size_t rowbase = (size_t)b * NP * NP;
    const float* dr = dist + rowbase + (size_t)p * NP;
    const float* br = bear + rowbase + (size_t)p * NP;
    const float* hr = head + rowbase + (size_t)p * NP;
    const int c0 = quad * 8;            // in-row column base for this lane

    // ---- batch-issue: 8 hidden f4 + 12 kb{0,1} f4, then fence ----
    const float4* hsrc = (const float4*)(hidden + (size_t)b * NP * ND);
    float4 hv[8];
    #pragma unroll
    for (int i = 0; i < 8; ++i) {
        int idx = i * 256 + ((tid & 15) * 16 + (tid >> 4));  // bijective perm
        hv[i] = hsrc[idx];
    }
    float4 La[12];
    #pragma unroll
    for (int k = 0; k < 2; ++k) {
        const int cc = k * 32 + c0;
        La[k * 6 + 0] = *(const float4*)(dr + cc);
        La[k * 6 + 1] = *(const float4*)(dr + cc + 4);
        La[k * 6 + 2] = *(const float4*)(br + cc);
        La[k * 6 + 3] = *(const float4*)(br + cc + 4);
        La[k * 6 + 4] = *(const float4*)(hr + cc);
        La[k * 6 + 5] = *(const float4*)(hr + cc + 4);
    }
    __builtin_amdgcn_sched_barrier(0);   // pin: 20 loads in flight, no sinking

    // ---- stage h: s_hT (transposed, swizzled perm) + h-cols of fused s_w ----
    #pragma unroll
    for (int i = 0; i < 8; ++i) {
        int idx = i * 256 + ((tid & 15) * 16 + (tid >> 4));
        int q = idx >> 4;            // 0..127
        int d = (idx & 15) * 4;      // 0..60
        short4 s4;
        s4.x = f2bf(hv[i].x); s4.y = f2bf(hv[i].y);
        s4.z = f2bf(hv[i].z); s4.w = f2bf(hv[i].w);
        s_hT[(d + 0) * SW + q] = s4.x;
        s_hT[(d + 1) * SW + q] = s4.y;
        s_hT[(d + 2) * SW + q] = s4.z;
        s_hT[(d + 3) * SW + q] = s4.w;
        int qloc = q - half * 64;
        if (qloc >= 0 && qloc < 64)   // h-cols of fused rows, natural layout
            *(short4*)&s_w[qloc * SW + 64 + d] = s4;
    }
    if (tid < 144) s_dom[tid] = domain[tid];
    if (tid < NP)  s_mask[tid] = smask[b * NP + tid];
    __syncthreads();   // the ONLY block-wide barrier (drains La batch too)

    // ---- issue kb{2,3} batch BEFORE computing kb{0,1}; fence ----
    float4 Lb[12];
    #pragma unroll
    for (int k = 0; k < 2; ++k) {
        const int cc = (k + 2) * 32 + c0;
        Lb[k * 6 + 0] = *(const float4*)(dr + cc);
        Lb[k * 6 + 1] = *(const float4*)(dr + cc + 4);
        Lb[k * 6 + 2] = *(const float4*)(br + cc);
        Lb[k * 6 + 3] = *(const float4*)(br + cc + 4);
        Lb[k * 6 + 4] = *(const float4*)(hr + cc);
        Lb[k * 6 + 5] = *(const float4*)(hr + cc + 4);
    }
    __builtin_amdgcn_sched_barrier(0);   // Lb stays issued here, in flight

    const float mp = s_mask[p];

    f32x4 acc[4], accs;
    #pragma unroll
    for (int tj = 0; tj < 4; ++tj) acc[tj] = (f32x4){0.f, 0.f, 0.f, 0.f};
    accs = (f32x4){0.f, 0.f, 0.f, 0.f};
    short8 ones;
    #pragma unroll
    for (int i = 0; i < 8; ++i) ones[i] = (short)0x3F80;  // bf16 1.0

    // ---- compute + MFMA for kb{0,1} (La ready; Lb latency hides here) ----
    #pragma unroll
    for (int k = 0; k < 2; ++k) {
        const int cc = k * 32 + c0;
        float4 m0 = *(const float4*)&s_mask[cc];
        float4 m1 = *(const float4*)&s_mask[cc + 4];
        short8 afr = calc_e8(La[k*6+0], La[k*6+1], La[k*6+2], La[k*6+3],
                             La[k*6+4], La[k*6+5], m0, m1, s_dom, mp, cc, p);
        const int ko = k * 32 + c0;
        accs = __builtin_amdgcn_mfma_f32_16x16x32_bf16(afr, ones, accs, 0, 0, 0);
        #pragma unroll
        for (int tj = 0; tj < 4; ++tj) {
            short8 bf = *(const short8*)&s_hT[(tj * 16 + l16) * SW + ko];
            acc[tj] = __builtin_amdgcn_mfma_f32_16x16x32_bf16(afr, bf, acc[tj], 0, 0, 0);
        }
    }
    // ---- compute + MFMA for kb{2,3} ----
    #pragma unroll
    for (int k = 0; k < 2; ++k) {
        const int cc = (k + 2) * 32 + c0;
        float4 m0 = *(const float4*)&s_mask[cc];
        float4 m1 = *(const float4*)&s_mask[cc + 4];
        short8 afr = calc_e8(Lb[k*6+0], Lb[k*6+1], Lb[k*6+2], Lb[k*6+3],
                             Lb[k*6+4], Lb[k*6+5], m0, m1, s_dom, mp, cc, p);
        const int ko = (k + 2) * 32 + c0;
        accs = __builtin_amdgcn_mfma_f32_16x16x32_bf16(afr, ones, accs, 0, 0, 0);
        #pragma unroll
        for (int tj = 0; tj < 4; ++tj) {
            short8 bf = *(const short8*)&s_hT[(tj * 16 + l16) * SW + ko];
            acc[tj] = __builtin_amdgcn_mfma_f32_16x16x32_bf16(afr, bf, acc[tj], 0, 0, 0);
        }
    }

    // C/D row = quad*4 + r; accs rows match lane-for-lane.
    float inv[4];
    #pragma unroll
    for (int r = 0; r < 4; ++r) inv[r] = 1.0f / (accs[r] + EPSF);

    // ---- wh into fused s_w (wave-local rows; DS is in-order per wave) ----
    #pragma unroll
    for (int tj = 0; tj < 4; ++tj)
        #pragma unroll
        for (int r = 0; r < 4; ++r) {
            int rw = R0L + quad * 4 + r;
            s_w[rw * SW + tj * 16 + l16] = f2bf(acc[tj][r] * inv[r]);
        }

    // ---- phase 3: out = tanh(fused @ W^T + b), B-frags from g_wbf (L2) ----
    f32x4 acc2[4];
    #pragma unroll
    for (int tj = 0; tj < 4; ++tj) acc2[tj] = (f32x4){0.f, 0.f, 0.f, 0.f};

    #pragma unroll
    for (int kb = 0; kb < 4; ++kb) {
        const int ko = kb * 32 + c0;
        short8 a = *(const short8*)&s_w[(R0L + l16) * SW + ko];
        #pragma unroll
        for (int tj = 0; tj < 4; ++tj) {
            short8 bf = *(const short8*)&g_wbf[(tj * 16 + l16) * (2 * ND) + ko];
            acc2[tj] = __builtin_amdgcn_mfma_f32_16x16x32_bf16(a, bf, acc2[tj], 0, 0, 0);
        }
    }

    float bvals[4];
    #pragma unroll
    for (int tj = 0; tj < 4; ++tj) bvals[tj] = bias[tj * 16 + l16];

    float* ob = out + ((size_t)b * NP + half * 64) * ND;
    #pragma unroll
    for (int tj = 0; tj < 4; ++tj)
        #pragma unroll
        for (int r = 0; r < 4; ++r) {
            int rw = R0L + quad * 4 + r;
            ob[(size_t)rw * ND + tj * 16 + l16] = fast_tanh(acc2[tj][r] + bvals[tj]);
        }
}

extern "C" void kernel_launch(void* const* d_in, const int* in_sizes, int n_in,
                              void* d_out, int out_size, void* d_ws, size_t ws_size,
                              hipStream_t stream) {
    const float* hidden = (const float*)d_in[0];
    const float* dist   = (const float*)d_in[1];
    const float* bear   = (const float*)d_in[2];
    const float* head   = (const float*)d_in[3];
    const float* smask  = (const float*)d_in[4];
    const float* domain = (const float*)d_in[5];
    const float* W      = (const float*)d_in[6];
    const float* bias   = (const float*)d_in[7];
    float* out = (float*)d_out;

    prep_w<<<dim3(8), dim3(256), 0, stream>>>(W);
    spatial_attn_kernel<<<dim3(NB * 2), dim3(256), 0, stream>>>(
        hidden, dist, bear, head, smask, domain, bias, out);
}